// Round 1
// baseline (936.541 us; speedup 1.0000x reference)
//
#include <hip/hip_runtime.h>
#include <hip/hip_bf16.h>

#define DI __device__ __forceinline__

typedef __attribute__((ext_vector_type(8))) short short8;   // 8 bf16 (4 VGPR)
typedef __attribute__((ext_vector_type(4))) short short4v;  // 4 bf16 (8B)
typedef __attribute__((ext_vector_type(4))) float floatx4;

constexpr int NN = 50000;
constexpr int NE = 500000;
constexpr int H  = 128;

// ws layout:
// [0)       W1f  bf16 12*8*64*8 = 49152 shorts
// [49152)   W2f  bf16  4*8*64*8 = 16384
// [65536)   Wn1f bf16  8*8*64*8 = 32768
// [98304)   Wn2f bf16  4*8*64*8 = 16384
// total shorts 114688 (229376 B), then 8 bias-frag arrays of 2048 f32 each.
constexpr int WF_TOTAL = 114688;
constexpr int BIASF_FLOATS = 8*2048;

DI short f2bf(float f){ __bf16 b = (__bf16)f; return __builtin_bit_cast(short, b); }

__global__ __launch_bounds__(256) void zero_kernel(float* __restrict__ p, int n4){
  int i = blockIdx.x*256 + threadIdx.x;
  if (i < n4) ((floatx4*)p)[i] = floatx4{0.f,0.f,0.f,0.f};
}

// Weights -> bf16 fragment-major: frag t=(ks*8+nt)*64+l, elem j  <->  W[32*ks+8*(l>>4)+j][16*nt+(l&15)]
// Biases  -> per-lane frag: [mt][l][r] = b[16*mt+4*(l>>4)+r]
__global__ __launch_bounds__(256) void prep_kernel(
    const float* __restrict__ We1, const float* __restrict__ We2,
    const float* __restrict__ Wn1, const float* __restrict__ Wn2,
    const float* __restrict__ be1, const float* __restrict__ be2,
    const float* __restrict__ ge,  const float* __restrict__ bge,
    const float* __restrict__ bn1, const float* __restrict__ bn2,
    const float* __restrict__ gn,  const float* __restrict__ bgn,
    short* __restrict__ wf, float* __restrict__ bf)
{
  int t = blockIdx.x*256 + threadIdx.x;
  if (t < WF_TOTAL) {
    const float* src; int base;
    if (t < 49152)      { src = We1; base = 0; }
    else if (t < 65536) { src = We2; base = 49152; }
    else if (t < 98304) { src = Wn1; base = 65536; }
    else                { src = Wn2; base = 98304; }
    int u = t - base;
    int j = u & 7, l = (u>>3)&63, nt = (u>>9)&7, ks = u>>12;
    int row = 32*ks + 8*(l>>4) + j;
    int col = 16*nt + (l&15);
    wf[t] = f2bf(src[row*H + col]);
  } else if (t < WF_TOTAL + BIASF_FLOATS) {
    int tb = t - WF_TOTAL;
    int arr = tb >> 11, u = tb & 2047;
    int r = u&3, l = (u>>2)&63, mt = u>>8;
    int feat = 16*mt + 4*(l>>4) + r;
    const float* s;
    switch (arr) {
      case 0: s = be1; break; case 1: s = be2; break;
      case 2: s = ge;  break; case 3: s = bge; break;
      case 4: s = bn1; break; case 5: s = bn2; break;
      case 6: s = gn;  break; default: s = bgn; break;
    }
    bf[tb] = s[feat];
  }
}

// One wave = 16 rows. Swapped-operand MFMA: D = W^T (A) x in^T (B), so
// lane l holds out[row=l&15][feat=16*mt+4*(l>>4)+r]. KS1 = K/32 of first GEMM.
template<int KS1, bool EDGE>
__global__ __launch_bounds__(256) void mlp_kernel(
    const int* __restrict__ edge_idx,
    const float* __restrict__ node_feats,
    const float* __restrict__ edge_feats,
    const short* __restrict__ w1f, const short* __restrict__ w2f,
    const float* __restrict__ b1f, const float* __restrict__ b2f,
    const float* __restrict__ gf,  const float* __restrict__ bgf,
    float* __restrict__ out_node, float* __restrict__ out_edge, int M)
{
  __shared__ short lds_h[4*2048];          // 4KB per wave, wave-private (no barrier)
  const int tid = threadIdx.x;
  const int w = tid>>6, l = tid&63, g = l>>4, lo = l&15;
  short* ldsw = lds_h + w*2048;

  const int row  = blockIdx.x*64 + w*16 + lo;
  const bool valid = row < M;
  const int rowc = valid ? row : (M-1);

  const float* sp0; const float* sp1; const float* sp2 = nullptr;
  int rcv = 0;
  if (EDGE) {
    int snd = edge_idx[2*rowc];
    rcv = edge_idx[2*rowc+1];
    sp0 = node_feats + (size_t)snd*H;      // sender feats   (K 0..127)
    sp1 = node_feats + (size_t)rcv*H;      // receiver feats (K 128..255)
    sp2 = edge_feats + (size_t)rowc*H;     // edge feats     (K 256..383)
  } else {
    sp0 = node_feats + (size_t)rowc*H;     // K 0..127
    sp1 = out_node  + (size_t)rowc*H;      // acc (segment sum), K 128..255
  }

  // ---- phase 1: h^T = W1^T @ e_in^T  (+be1 via acc init) ----
  floatx4 acc1[8];
#pragma unroll
  for (int mt=0; mt<8; ++mt) acc1[mt] = *(const floatx4*)(b1f + (mt*64+l)*4);

#pragma unroll
  for (int ks=0; ks<KS1; ++ks) {
    const float* sp = (ks>>2)==0 ? sp0 : ((ks>>2)==1 ? sp1 : sp2);
    const int koff = (ks&3)*32 + g*8;
    floatx4 f0 = *(const floatx4*)(sp + koff);
    floatx4 f1 = *(const floatx4*)(sp + koff + 4);
    short8 ein;
    ein[0]=f2bf(f0[0]); ein[1]=f2bf(f0[1]); ein[2]=f2bf(f0[2]); ein[3]=f2bf(f0[3]);
    ein[4]=f2bf(f1[0]); ein[5]=f2bf(f1[1]); ein[6]=f2bf(f1[2]); ein[7]=f2bf(f1[3]);
#pragma unroll
    for (int mt=0; mt<8; ++mt) {
      short8 wv = *(const short8*)(w1f + ((ks*8+mt)*64 + l)*8);
      acc1[mt] = __builtin_amdgcn_mfma_f32_16x16x32_bf16(wv, ein, acc1[mt], 0,0,0);
    }
  }

  // ---- relu + bf16 pack to LDS as h[edge=lo][feat], XOR-swizzled (16B granular) ----
#pragma unroll
  for (int mt=0; mt<8; ++mt) {
    short4v hv;
#pragma unroll
    for (int r=0; r<4; ++r) {
      float v = acc1[mt][r];
      hv[r] = f2bf(v > 0.f ? v : 0.f);
    }
    int off = (lo*256 + mt*32 + g*8) ^ ((lo&7)<<4);
    *(short4v*)((char*)ldsw + off) = hv;
  }

  // ---- phase 2: y^T = W2^T @ h^T (+be2 via acc init) ----
  floatx4 acc2[8];
#pragma unroll
  for (int mt=0; mt<8; ++mt) acc2[mt] = *(const floatx4*)(b2f + (mt*64+l)*4);

#pragma unroll
  for (int s=0; s<4; ++s) {
    int roff = (lo*256 + s*64 + g*16) ^ ((lo&7)<<4);
    short8 hb = *(const short8*)((char*)ldsw + roff);   // shared across all 8 mt
#pragma unroll
    for (int mt=0; mt<8; ++mt) {
      short8 wv = *(const short8*)(w2f + ((s*8+mt)*64 + l)*8);
      acc2[mt] = __builtin_amdgcn_mfma_f32_16x16x32_bf16(wv, hb, acc2[mt], 0,0,0);
    }
  }

  // ---- LayerNorm: row lives in 4 lanes (xor 16/32 butterfly) ----
  float sum = 0.f, ssq = 0.f;
#pragma unroll
  for (int mt=0; mt<8; ++mt)
#pragma unroll
    for (int r=0; r<4; ++r) { float v = acc2[mt][r]; sum += v; ssq += v*v; }
  sum += __shfl_xor(sum, 16); ssq += __shfl_xor(ssq, 16);
  sum += __shfl_xor(sum, 32); ssq += __shfl_xor(ssq, 32);
  const float mean = sum * (1.f/H);
  const float var  = ssq * (1.f/H) - mean*mean;
  const float rs   = rsqrtf(var + 1e-5f);

  const float* resid = EDGE ? (edge_feats + (size_t)rowc*H) : (node_feats + (size_t)rowc*H);
  float* outp = EDGE ? (out_edge + (size_t)rowc*H) : (out_node + (size_t)rowc*H);

#pragma unroll
  for (int mt=0; mt<8; ++mt) {
    floatx4 gv  = *(const floatx4*)(gf  + (mt*64+l)*4);
    floatx4 bgv = *(const floatx4*)(bgf + (mt*64+l)*4);
    floatx4 ef  = *(const floatx4*)(resid + mt*16 + g*4);
    floatx4 o;
#pragma unroll
    for (int r=0; r<4; ++r) o[r] = ef[r] + (acc2[mt][r]-mean)*rs*gv[r] + bgv[r];
    if (valid) {
      *(floatx4*)(outp + mt*16 + g*4) = o;
      if (EDGE) {
        float* ap = out_node + (size_t)rcv*H + mt*16 + g*4;   // fused segment_sum
#pragma unroll
        for (int r=0; r<4; ++r) unsafeAtomicAdd(ap + r, ef[r]);
      }
    }
  }
}

extern "C" void kernel_launch(void* const* d_in, const int* in_sizes, int n_in,
                              void* d_out, int out_size, void* d_ws, size_t ws_size,
                              hipStream_t stream)
{
  const int*   edge_idx   = (const int*)  d_in[0];
  const float* node_feats = (const float*)d_in[1];
  const float* edge_feats = (const float*)d_in[2];
  const float* We1=(const float*)d_in[3];  const float* be1=(const float*)d_in[4];
  const float* We2=(const float*)d_in[5];  const float* be2=(const float*)d_in[6];
  const float* ge =(const float*)d_in[7];  const float* bge=(const float*)d_in[8];
  const float* Wn1=(const float*)d_in[9];  const float* bn1=(const float*)d_in[10];
  const float* Wn2=(const float*)d_in[11]; const float* bn2=(const float*)d_in[12];
  const float* gn =(const float*)d_in[13]; const float* bgn=(const float*)d_in[14];

  float* out_node = (float*)d_out;                    // doubles as segment-sum acc
  float* out_edge = out_node + (size_t)NN*H;

  short* wf = (short*)d_ws;
  float* bf = (float*)((char*)d_ws + (size_t)WF_TOTAL*sizeof(short));
  short* w1f  = wf;
  short* w2f  = wf + 49152;
  short* wn1f = wf + 65536;
  short* wn2f = wf + 98304;
  float* b1f  = bf;         float* b2f  = bf + 2048;
  float* gef  = bf + 4096;  float* bgef = bf + 6144;
  float* bn1f = bf + 8192;  float* bn2f = bf + 10240;
  float* gnf  = bf + 12288; float* bgnf = bf + 14336;

  zero_kernel<<<(NN*H/4 + 255)/256, 256, 0, stream>>>(out_node, NN*H/4);
  prep_kernel<<<(WF_TOTAL + BIASF_FLOATS + 255)/256, 256, 0, stream>>>(
      We1, We2, Wn1, Wn2, be1, be2, ge, bge, bn1, bn2, gn, bgn, wf, bf);

  mlp_kernel<12, true><<<(NE+63)/64, 256, 0, stream>>>(
      edge_idx, node_feats, edge_feats, w1f, w2f, b1f, b2f, gef, bgef,
      out_node, out_edge, NE);
  mlp_kernel<8, false><<<(NN+63)/64, 256, 0, stream>>>(
      nullptr, node_feats, edge_feats, wn1f, wn2f, bn1f, bn2f, gnf, bgnf,
      out_node, out_edge, NN);
}

// Round 2
// 607.778 us; speedup vs baseline: 1.5409x; 1.5409x over previous
//
#include <hip/hip_runtime.h>
#include <hip/hip_bf16.h>

#define DI __device__ __forceinline__

typedef __attribute__((ext_vector_type(8))) short short8;   // 8 bf16 (4 VGPR)
typedef __attribute__((ext_vector_type(4))) short short4v;  // 4 bf16 (8B)
typedef __attribute__((ext_vector_type(4))) float floatx4;

constexpr int NN = 50000;
constexpr int NE = 500000;
constexpr int H  = 128;
constexpr int NB1 = (NN + 255) / 256;   // 196 scan blocks

// ws layout (bytes):
// [0)        wf   bf16 fragments, 114688 shorts = 229376 B
// [229376)   bf   bias fragments, 16384 floats  =  65536 B
// [294912)   cnt      int[50000]
// [494912)   tmp      int[50000]   (per-element inclusive scan)
// [694912)   rowstart int[50000]
// [894912)   cursor   int[50000]
// [1094912)  blocksum int[256]
// [1095936)  csr      int[500000]
constexpr int WF_TOTAL = 114688;
constexpr int BIASF_FLOATS = 8*2048;

DI short f2bf(float f){ __bf16 b = (__bf16)f; return __builtin_bit_cast(short, b); }

__global__ __launch_bounds__(256) void zero_cnt_kernel(int* __restrict__ cnt){
  int i = blockIdx.x*256 + threadIdx.x;
  if (i < NN) cnt[i] = 0;
}

// Weights -> bf16 fragment-major: frag t=(ks*8+nt)*64+l, elem j  <->  W[32*ks+8*(l>>4)+j][16*nt+(l&15)]
// Biases  -> per-lane frag: [mt][l][r] = b[16*mt+4*(l>>4)+r]
__global__ __launch_bounds__(256) void prep_kernel(
    const float* __restrict__ We1, const float* __restrict__ We2,
    const float* __restrict__ Wn1, const float* __restrict__ Wn2,
    const float* __restrict__ be1, const float* __restrict__ be2,
    const float* __restrict__ ge,  const float* __restrict__ bge,
    const float* __restrict__ bn1, const float* __restrict__ bn2,
    const float* __restrict__ gn,  const float* __restrict__ bgn,
    short* __restrict__ wf, float* __restrict__ bf)
{
  int t = blockIdx.x*256 + threadIdx.x;
  if (t < WF_TOTAL) {
    const float* src; int base;
    if (t < 49152)      { src = We1; base = 0; }
    else if (t < 65536) { src = We2; base = 49152; }
    else if (t < 98304) { src = Wn1; base = 65536; }
    else                { src = Wn2; base = 98304; }
    int u = t - base;
    int j = u & 7, l = (u>>3)&63, nt = (u>>9)&7, ks = u>>12;
    int row = 32*ks + 8*(l>>4) + j;
    int col = 16*nt + (l&15);
    wf[t] = f2bf(src[row*H + col]);
  } else if (t < WF_TOTAL + BIASF_FLOATS) {
    int tb = t - WF_TOTAL;
    int arr = tb >> 11, u = tb & 2047;
    int r = u&3, l = (u>>2)&63, mt = u>>8;
    int feat = 16*mt + 4*(l>>4) + r;
    const float* s;
    switch (arr) {
      case 0: s = be1; break; case 1: s = be2; break;
      case 2: s = ge;  break; case 3: s = bge; break;
      case 4: s = bn1; break; case 5: s = bn2; break;
      case 6: s = gn;  break; default: s = bgn; break;
    }
    bf[tb] = s[feat];
  }
}

// ---------- CSR build ----------
__global__ __launch_bounds__(256) void hist_kernel(const int* __restrict__ ei, int* __restrict__ cnt){
  int e = blockIdx.x*256 + threadIdx.x;
  if (e < NE) atomicAdd(&cnt[ei[2*e+1]], 1);
}

__global__ __launch_bounds__(256) void scan1_kernel(const int* __restrict__ cnt,
                                                    int* __restrict__ tmp, int* __restrict__ blocksum){
  __shared__ int s[256];
  int t = threadIdx.x, i = blockIdx.x*256 + t;
  int v = (i < NN) ? cnt[i] : 0;
  s[t] = v; __syncthreads();
#pragma unroll
  for (int o=1; o<256; o<<=1){
    int u = (t >= o) ? s[t-o] : 0;
    __syncthreads();
    s[t] += u;
    __syncthreads();
  }
  if (i < NN) tmp[i] = s[t];
  if (t == 255) blocksum[blockIdx.x] = s[255];
}

__global__ __launch_bounds__(256) void scan2_kernel(int* __restrict__ blocksum){
  __shared__ int s[256];
  int t = threadIdx.x;
  int v = (t < NB1) ? blocksum[t] : 0;
  s[t] = v; __syncthreads();
#pragma unroll
  for (int o=1; o<256; o<<=1){
    int u = (t >= o) ? s[t-o] : 0;
    __syncthreads();
    s[t] += u;
    __syncthreads();
  }
  if (t < NB1) blocksum[t] = s[t] - v;   // exclusive
}

__global__ __launch_bounds__(256) void scan3_kernel(const int* __restrict__ cnt, const int* __restrict__ tmp,
                                                    const int* __restrict__ blocksum,
                                                    int* __restrict__ rowstart, int* __restrict__ cursor){
  int i = blockIdx.x*256 + threadIdx.x;
  if (i < NN){
    int rs = tmp[i] - cnt[i] + blocksum[blockIdx.x];
    rowstart[i] = rs; cursor[i] = rs;
  }
}

__global__ __launch_bounds__(256) void scatter_kernel(const int* __restrict__ ei,
                                                      int* __restrict__ cursor, int* __restrict__ csr){
  int e = blockIdx.x*256 + threadIdx.x;
  if (e < NE){
    int r = ei[2*e+1];
    int p = atomicAdd(&cursor[r], 1);
    csr[p] = e;
  }
}

// one wave per node: lane l owns feats {2l, 2l+1}
__global__ __launch_bounds__(256) void segsum_kernel(const int* __restrict__ csr,
                                                     const int* __restrict__ rowstart,
                                                     const int* __restrict__ cnt,
                                                     const float* __restrict__ edge_feats,
                                                     float* __restrict__ acc){
  int w = threadIdx.x>>6, l = threadIdx.x&63;
  int n = blockIdx.x*4 + w;
  if (n >= NN) return;
  int start = rowstart[n], deg = cnt[n];
  float sx = 0.f, sy = 0.f;
  for (int k=0; k<deg; ++k){
    int e = csr[start+k];
    const float2 v = *(const float2*)(edge_feats + (size_t)e*H + 2*l);
    sx += v.x; sy += v.y;
  }
  *(float2*)(acc + (size_t)n*H + 2*l) = float2{sx, sy};
}

// ---------- fused 2-layer MLP + LN + residual ----------
// One wave = R batches of 16 rows. Swapped-operand MFMA: lane l holds
// out[row=l&15][feat=16*mt+4*(l>>4)+r]. Weight fragments shared across batches.
template<int KS1, bool EDGE, int R>
__global__ __launch_bounds__(256) void mlp_kernel(
    const int* __restrict__ edge_idx,
    const float* __restrict__ node_feats,
    const float* __restrict__ edge_feats,
    const short* __restrict__ w1f, const short* __restrict__ w2f,
    const float* __restrict__ b1f, const float* __restrict__ b2f,
    const float* __restrict__ gf,  const float* __restrict__ bgf,
    float* __restrict__ out_node, float* __restrict__ out_edge, int M)
{
  __shared__ short lds_h[4*R*2048];          // 4KB per (wave,batch), wave-private
  const int tid = threadIdx.x;
  const int w = tid>>6, l = tid&63, g = l>>4, lo = l&15;

  int rowc[R]; bool valid[R];
  const float *sp0[R], *sp1[R], *sp2[R];
#pragma unroll
  for (int b=0; b<R; ++b){
    int row = blockIdx.x*(64*R) + w*(16*R) + b*16 + lo;
    valid[b] = row < M;
    rowc[b]  = valid[b] ? row : (M-1);
    if (EDGE){
      int snd = edge_idx[2*rowc[b]];
      int rcv = edge_idx[2*rowc[b]+1];
      sp0[b] = node_feats + (size_t)snd*H;
      sp1[b] = node_feats + (size_t)rcv*H;
      sp2[b] = edge_feats + (size_t)rowc[b]*H;
    } else {
      sp0[b] = node_feats + (size_t)rowc[b]*H;
      sp1[b] = out_node   + (size_t)rowc[b]*H;   // acc (segment sum)
      sp2[b] = nullptr;
    }
  }

  // ---- phase 1: h^T = W1^T @ e_in^T (+b1 via acc init) ----
  floatx4 acc1[R][8];
#pragma unroll
  for (int mt=0; mt<8; ++mt){
    floatx4 bv = *(const floatx4*)(b1f + (mt*64+l)*4);
#pragma unroll
    for (int b=0; b<R; ++b) acc1[b][mt] = bv;
  }

#pragma unroll
  for (int ks=0; ks<KS1; ++ks){
    const int koff = (ks&3)*32 + g*8;
    short8 ein[R];
#pragma unroll
    for (int b=0; b<R; ++b){
      const float* sp = (ks>>2)==0 ? sp0[b] : ((ks>>2)==1 ? sp1[b] : sp2[b]);
      floatx4 f0 = *(const floatx4*)(sp + koff);
      floatx4 f1 = *(const floatx4*)(sp + koff + 4);
      ein[b][0]=f2bf(f0[0]); ein[b][1]=f2bf(f0[1]); ein[b][2]=f2bf(f0[2]); ein[b][3]=f2bf(f0[3]);
      ein[b][4]=f2bf(f1[0]); ein[b][5]=f2bf(f1[1]); ein[b][6]=f2bf(f1[2]); ein[b][7]=f2bf(f1[3]);
    }
#pragma unroll
    for (int mt=0; mt<8; ++mt){
      short8 wv = *(const short8*)(w1f + ((ks*8+mt)*64 + l)*8);
#pragma unroll
      for (int b=0; b<R; ++b)
        acc1[b][mt] = __builtin_amdgcn_mfma_f32_16x16x32_bf16(wv, ein[b], acc1[b][mt], 0,0,0);
    }
  }

  // ---- relu + bf16 pack to LDS as h[row=lo][feat], XOR-swizzled ----
#pragma unroll
  for (int b=0; b<R; ++b){
    short* ldsw = lds_h + (w*R + b)*2048;
#pragma unroll
    for (int mt=0; mt<8; ++mt){
      short4v hv;
#pragma unroll
      for (int r=0; r<4; ++r){
        float v = acc1[b][mt][r];
        hv[r] = f2bf(v > 0.f ? v : 0.f);
      }
      int off = (lo*256 + mt*32 + g*8) ^ ((lo&7)<<4);
      *(short4v*)((char*)ldsw + off) = hv;
    }
  }

  // ---- phase 2: y^T = W2^T @ h^T (+b2 via acc init) ----
  floatx4 acc2[R][8];
#pragma unroll
  for (int mt=0; mt<8; ++mt){
    floatx4 bv = *(const floatx4*)(b2f + (mt*64+l)*4);
#pragma unroll
    for (int b=0; b<R; ++b) acc2[b][mt] = bv;
  }

#pragma unroll
  for (int s=0; s<4; ++s){
    short8 hb[R];
#pragma unroll
    for (int b=0; b<R; ++b){
      short* ldsw = lds_h + (w*R + b)*2048;
      int roff = (lo*256 + s*64 + g*16) ^ ((lo&7)<<4);
      hb[b] = *(const short8*)((char*)ldsw + roff);
    }
#pragma unroll
    for (int mt=0; mt<8; ++mt){
      short8 wv = *(const short8*)(w2f + ((s*8+mt)*64 + l)*8);
#pragma unroll
      for (int b=0; b<R; ++b)
        acc2[b][mt] = __builtin_amdgcn_mfma_f32_16x16x32_bf16(wv, hb[b], acc2[b][mt], 0,0,0);
    }
  }

  // ---- LayerNorm (row lives in 4 lanes: xor 16/32 butterfly) + residual + store ----
  float meanv[R], rsv[R];
#pragma unroll
  for (int b=0; b<R; ++b){
    float sum = 0.f, ssq = 0.f;
#pragma unroll
    for (int mt=0; mt<8; ++mt)
#pragma unroll
      for (int r=0; r<4; ++r){ float v = acc2[b][mt][r]; sum += v; ssq += v*v; }
    sum += __shfl_xor(sum, 16); ssq += __shfl_xor(ssq, 16);
    sum += __shfl_xor(sum, 32); ssq += __shfl_xor(ssq, 32);
    meanv[b] = sum * (1.f/H);
    float var = ssq * (1.f/H) - meanv[b]*meanv[b];
    rsv[b] = rsqrtf(var + 1e-5f);
  }

#pragma unroll
  for (int mt=0; mt<8; ++mt){
    floatx4 gv  = *(const floatx4*)(gf  + (mt*64+l)*4);
    floatx4 bgv = *(const floatx4*)(bgf + (mt*64+l)*4);
#pragma unroll
    for (int b=0; b<R; ++b){
      const float* resid = EDGE ? (edge_feats + (size_t)rowc[b]*H) : (node_feats + (size_t)rowc[b]*H);
      floatx4 ef = *(const floatx4*)(resid + mt*16 + g*4);
      floatx4 o;
#pragma unroll
      for (int r=0; r<4; ++r) o[r] = ef[r] + (acc2[b][mt][r]-meanv[b])*rsv[b]*gv[r] + bgv[r];
      if (valid[b]){
        float* outp = EDGE ? (out_edge + (size_t)rowc[b]*H) : (out_node + (size_t)rowc[b]*H);
        *(floatx4*)(outp + mt*16 + g*4) = o;
      }
    }
  }
}

extern "C" void kernel_launch(void* const* d_in, const int* in_sizes, int n_in,
                              void* d_out, int out_size, void* d_ws, size_t ws_size,
                              hipStream_t stream)
{
  const int*   edge_idx   = (const int*)  d_in[0];
  const float* node_feats = (const float*)d_in[1];
  const float* edge_feats = (const float*)d_in[2];
  const float* We1=(const float*)d_in[3];  const float* be1=(const float*)d_in[4];
  const float* We2=(const float*)d_in[5];  const float* be2=(const float*)d_in[6];
  const float* ge =(const float*)d_in[7];  const float* bge=(const float*)d_in[8];
  const float* Wn1=(const float*)d_in[9];  const float* bn1=(const float*)d_in[10];
  const float* Wn2=(const float*)d_in[11]; const float* bn2=(const float*)d_in[12];
  const float* gn =(const float*)d_in[13]; const float* bgn=(const float*)d_in[14];

  float* out_node = (float*)d_out;                    // doubles as segment-sum acc
  float* out_edge = out_node + (size_t)NN*H;

  char* ws = (char*)d_ws;
  short* wf      = (short*)ws;
  float* bf      = (float*)(ws + 229376);
  int* cnt       = (int*)(ws + 294912);
  int* tmp       = (int*)(ws + 494912);
  int* rowstart  = (int*)(ws + 694912);
  int* cursor    = (int*)(ws + 894912);
  int* blocksum  = (int*)(ws + 1094912);
  int* csr       = (int*)(ws + 1095936);

  short* w1f  = wf;
  short* w2f  = wf + 49152;
  short* wn1f = wf + 65536;
  short* wn2f = wf + 98304;
  float* b1f  = bf;         float* b2f  = bf + 2048;
  float* gef  = bf + 4096;  float* bgef = bf + 6144;
  float* bn1f = bf + 8192;  float* bn2f = bf + 10240;
  float* gnf  = bf + 12288; float* bgnf = bf + 14336;

  zero_cnt_kernel<<<NB1, 256, 0, stream>>>(cnt);
  prep_kernel<<<(WF_TOTAL + BIASF_FLOATS + 255)/256, 256, 0, stream>>>(
      We1, We2, Wn1, Wn2, be1, be2, ge, bge, bn1, bn2, gn, bgn, wf, bf);

  // CSR build
  hist_kernel<<<(NE+255)/256, 256, 0, stream>>>(edge_idx, cnt);
  scan1_kernel<<<NB1, 256, 0, stream>>>(cnt, tmp, blocksum);
  scan2_kernel<<<1, 256, 0, stream>>>(blocksum);
  scan3_kernel<<<NB1, 256, 0, stream>>>(cnt, tmp, blocksum, rowstart, cursor);
  scatter_kernel<<<(NE+255)/256, 256, 0, stream>>>(edge_idx, cursor, csr);

  // edge MLP (atomic-free now), R=2 batches/wave sharing weight fragments
  mlp_kernel<12, true, 2><<<(NE + 127)/128, 256, 0, stream>>>(
      edge_idx, node_feats, edge_feats, w1f, w2f, b1f, b2f, gef, bgef,
      out_node, out_edge, NE);

  // segment_sum via CSR into out_node (acc), then node MLP consumes + overwrites
  segsum_kernel<<<(NN+3)/4, 256, 0, stream>>>(csr, rowstart, cnt, edge_feats, out_node);

  mlp_kernel<8, false, 1><<<(NN+63)/64, 256, 0, stream>>>(
      nullptr, node_feats, edge_feats, wn1f, wn2f, bn1f, bn2f, gnf, bgnf,
      out_node, out_edge, NN);
}

// Round 3
// 466.441 us; speedup vs baseline: 2.0078x; 1.3030x over previous
//
#include <hip/hip_runtime.h>
#include <hip/hip_bf16.h>

#define DI __device__ __forceinline__

typedef __attribute__((ext_vector_type(8))) short short8;   // 8 bf16 (4 VGPR)
typedef __attribute__((ext_vector_type(4))) short short4v;  // 4 bf16 (8B)
typedef __attribute__((ext_vector_type(4))) float floatx4;

constexpr int NN = 50000;
constexpr int NE = 500000;
constexpr int H  = 128;
constexpr int NB1 = (NN + 255) / 256;   // scan blocks

// ---- ws layout (bytes) ----
// wf   (bf16 weight frags, 7 blocks of 16384 shorts; Wn1 = blocks 4+5): [0, 229376)
// bf   (bias frags, 8*2048 f32):                                       [229376, 294912)
// Ps   (bf16, NN*128, permuted feat layout):                           [294912, 13094912)
// Pr   (bf16, NN*128):                                                 [13094912, 25894912)
// cnt/tmp/rowstart/cursor int[50000] each; blocksum int[256]; csr int[500000]
constexpr size_t OFF_BF   = 229376;
constexpr size_t OFF_PS   = 294912;
constexpr size_t OFF_PR   = 13094912;
constexpr size_t OFF_CNT  = 25894912;
constexpr size_t OFF_TMP  = 26094912;
constexpr size_t OFF_RS   = 26294912;
constexpr size_t OFF_CUR  = 26494912;
constexpr size_t OFF_BSUM = 26694912;
constexpr size_t OFF_CSR  = 26695936;

constexpr int WF_TOTAL = 114688;      // 7*16384 shorts
constexpr int BIASF_FLOATS = 8*2048;

DI short f2bf(float f){ __bf16 b = (__bf16)f; return __builtin_bit_cast(short, b); }
DI float bf2f(short s){ return __builtin_bit_cast(float, ((unsigned)(unsigned short)s) << 16); }

__global__ __launch_bounds__(256) void zero_cnt_kernel(int* __restrict__ cnt){
  int i = blockIdx.x*256 + threadIdx.x;
  if (i < NN) cnt[i] = 0;
}

// Weight frags: within a 16384-short block: t=((ks*8+nt)*64+l)*8+j <-> W[roff+32ks+8(l>>4)+j][16nt+(l&15)]
// blocks: 0 We1+0 (W_s) | 1 We1+128 (W_r) | 2 We1+256 (W_e) | 3 We2 | 4 Wn1+0 | 5 Wn1+128 | 6 Wn2
__global__ __launch_bounds__(256) void prep_kernel(
    const float* __restrict__ We1, const float* __restrict__ We2,
    const float* __restrict__ Wn1, const float* __restrict__ Wn2,
    const float* __restrict__ be1, const float* __restrict__ be2,
    const float* __restrict__ ge,  const float* __restrict__ bge,
    const float* __restrict__ bn1, const float* __restrict__ bn2,
    const float* __restrict__ gn,  const float* __restrict__ bgn,
    short* __restrict__ wf, float* __restrict__ bf)
{
  int t = blockIdx.x*256 + threadIdx.x;
  if (t < WF_TOTAL) {
    int blk = t >> 14, u = t & 16383;
    int j = u & 7, l = (u>>3)&63, nt = (u>>9)&7, ks = u>>12;
    const float* src; int roff;
    switch (blk) {
      case 0: src = We1; roff = 0;   break;
      case 1: src = We1; roff = 128; break;
      case 2: src = We1; roff = 256; break;
      case 3: src = We2; roff = 0;   break;
      case 4: src = Wn1; roff = 0;   break;
      case 5: src = Wn1; roff = 128; break;
      default: src = Wn2; roff = 0;  break;
    }
    int row = roff + 32*ks + 8*(l>>4) + j;
    int col = 16*nt + (l&15);
    wf[t] = f2bf(src[row*H + col]);
  } else if (t < WF_TOTAL + BIASF_FLOATS) {
    int tb = t - WF_TOTAL;
    int arr = tb >> 11, u = tb & 2047;
    int r = u&3, l = (u>>2)&63, mt = u>>8;
    int feat = 16*mt + 4*(l>>4) + r;
    const float* s;
    switch (arr) {
      case 0: s = be1; break; case 1: s = be2; break;
      case 2: s = ge;  break; case 3: s = bge; break;
      case 4: s = bn1; break; case 5: s = bn2; break;
      case 6: s = gn;  break; default: s = bgn; break;
    }
    bf[tb] = s[feat];
  }
}

// ---------- CSR build ----------
__global__ __launch_bounds__(256) void hist_kernel(const int* __restrict__ ei, int* __restrict__ cnt){
  int e = blockIdx.x*256 + threadIdx.x;
  if (e < NE) atomicAdd(&cnt[ei[2*e+1]], 1);
}

__global__ __launch_bounds__(256) void scan1_kernel(const int* __restrict__ cnt,
                                                    int* __restrict__ tmp, int* __restrict__ blocksum){
  __shared__ int s[256];
  int t = threadIdx.x, i = blockIdx.x*256 + t;
  int v = (i < NN) ? cnt[i] : 0;
  s[t] = v; __syncthreads();
#pragma unroll
  for (int o=1; o<256; o<<=1){
    int u = (t >= o) ? s[t-o] : 0;
    __syncthreads();
    s[t] += u;
    __syncthreads();
  }
  if (i < NN) tmp[i] = s[t];
  if (t == 255) blocksum[blockIdx.x] = s[255];
}

__global__ __launch_bounds__(256) void scan2_kernel(int* __restrict__ blocksum){
  __shared__ int s[256];
  int t = threadIdx.x;
  int v = (t < NB1) ? blocksum[t] : 0;
  s[t] = v; __syncthreads();
#pragma unroll
  for (int o=1; o<256; o<<=1){
    int u = (t >= o) ? s[t-o] : 0;
    __syncthreads();
    s[t] += u;
    __syncthreads();
  }
  if (t < NB1) blocksum[t] = s[t] - v;   // exclusive
}

__global__ __launch_bounds__(256) void scan3_kernel(const int* __restrict__ cnt, const int* __restrict__ tmp,
                                                    const int* __restrict__ blocksum,
                                                    int* __restrict__ rowstart, int* __restrict__ cursor){
  int i = blockIdx.x*256 + threadIdx.x;
  if (i < NN){
    int rs = tmp[i] - cnt[i] + blocksum[blockIdx.x];
    rowstart[i] = rs; cursor[i] = rs;
  }
}

__global__ __launch_bounds__(256) void scatter_kernel(const int* __restrict__ ei,
                                                      int* __restrict__ cursor, int* __restrict__ csr){
  int e = blockIdx.x*256 + threadIdx.x;
  if (e < NE){
    int r = ei[2*e+1];
    int p = atomicAdd(&cursor[r], 1);
    csr[p] = e;
  }
}

// one wave per node: lane l owns feats {2l, 2l+1}
__global__ __launch_bounds__(256) void segsum_kernel(const int* __restrict__ csr,
                                                     const int* __restrict__ rowstart,
                                                     const int* __restrict__ cnt,
                                                     const float* __restrict__ edge_feats,
                                                     float* __restrict__ acc){
  int w = threadIdx.x>>6, l = threadIdx.x&63;
  int n = blockIdx.x*4 + w;
  if (n >= NN) return;
  int start = rowstart[n], deg = cnt[n];
  float sx = 0.f, sy = 0.f;
  for (int k=0; k<deg; ++k){
    int e = csr[start+k];
    const float2 v = *(const float2*)(edge_feats + (size_t)e*H + 2*l);
    sx += v.x; sy += v.y;
  }
  *(float2*)(acc + (size_t)n*H + 2*l) = float2{sx, sy};
}

// ---------- P projections: Ps = node_feats @ W_s, Pr = node_feats @ W_r (bf16, permuted) ----------
// Output pos(feat) = g*32 + mt*4 + r where feat = 16mt+4g+r. Lane l stores its acc[mt][0..3]
// at row*128 + (l>>4)*32 + mt*4. Edge kernel loads 16B (= 2 mt) per lane.
__global__ __launch_bounds__(256) void pproj_kernel(
    const float* __restrict__ node_feats,
    const short* __restrict__ wsf, const short* __restrict__ wrf,
    short* __restrict__ Ps, short* __restrict__ Pr)
{
  const int tid = threadIdx.x;
  const int w = tid>>6, l = tid&63, g = l>>4, lo = l&15;
  int row = blockIdx.x*64 + w*16 + lo;
  bool valid = row < NN;
  int rowc = valid ? row : (NN-1);
  const float* sp = node_feats + (size_t)rowc*H;

  short8 ein[4];
#pragma unroll
  for (int ks=0; ks<4; ++ks){
    const int koff = ks*32 + g*8;
    floatx4 f0 = *(const floatx4*)(sp + koff);
    floatx4 f1 = *(const floatx4*)(sp + koff + 4);
    ein[ks][0]=f2bf(f0[0]); ein[ks][1]=f2bf(f0[1]); ein[ks][2]=f2bf(f0[2]); ein[ks][3]=f2bf(f0[3]);
    ein[ks][4]=f2bf(f1[0]); ein[ks][5]=f2bf(f1[1]); ein[ks][6]=f2bf(f1[2]); ein[ks][7]=f2bf(f1[3]);
  }

  floatx4 as[8], ar[8];
#pragma unroll
  for (int mt=0; mt<8; ++mt){ as[mt] = floatx4{0,0,0,0}; ar[mt] = floatx4{0,0,0,0}; }
#pragma unroll
  for (int ks=0; ks<4; ++ks){
#pragma unroll
    for (int mt=0; mt<8; ++mt){
      short8 wv = *(const short8*)(wsf + ((ks*8+mt)*64 + l)*8);
      as[mt] = __builtin_amdgcn_mfma_f32_16x16x32_bf16(wv, ein[ks], as[mt], 0,0,0);
      short8 wv2 = *(const short8*)(wrf + ((ks*8+mt)*64 + l)*8);
      ar[mt] = __builtin_amdgcn_mfma_f32_16x16x32_bf16(wv2, ein[ks], ar[mt], 0,0,0);
    }
  }

  if (valid){
    short* ps = Ps + (size_t)rowc*H + g*32;
    short* pr = Pr + (size_t)rowc*H + g*32;
#pragma unroll
    for (int mt=0; mt<8; ++mt){
      short4v vs, vr;
#pragma unroll
      for (int r=0; r<4; ++r){ vs[r] = f2bf(as[mt][r]); vr[r] = f2bf(ar[mt][r]); }
      *(short4v*)(ps + mt*4) = vs;
      *(short4v*)(pr + mt*4) = vr;
    }
  }
}

// ---------- edge kernel: acc = b1 + Ps[snd] + Pr[rcv] + ef@W_e; relu; @W2; LN; +resid ----------
template<int R>
__global__ __launch_bounds__(256) void edge_kernel(
    const int* __restrict__ edge_idx,
    const float* __restrict__ edge_feats,
    const short* __restrict__ Ps, const short* __restrict__ Pr,
    const short* __restrict__ wef, const short* __restrict__ w2f,
    const float* __restrict__ b1f, const float* __restrict__ b2f,
    const float* __restrict__ gf,  const float* __restrict__ bgf,
    float* __restrict__ out_edge)
{
  __shared__ short lds_h[4*R*2048];          // 4KB per (wave,batch), wave-private
  const int tid = threadIdx.x;
  const int w = tid>>6, l = tid&63, g = l>>4, lo = l&15;

  int rowc[R]; bool valid[R]; int snd[R], rcv[R];
#pragma unroll
  for (int b=0; b<R; ++b){
    int row = blockIdx.x*(64*R) + w*(16*R) + b*16 + lo;
    valid[b] = row < NE;
    rowc[b]  = valid[b] ? row : (NE-1);
    snd[b] = edge_idx[2*rowc[b]];
    rcv[b] = edge_idx[2*rowc[b]+1];
  }

  // ---- phase 1: bias + gather-add of Ps/Pr + ef@W_e ----
  floatx4 acc1[R][8];
#pragma unroll
  for (int mt=0; mt<8; ++mt){
    floatx4 bv = *(const floatx4*)(b1f + (mt*64+l)*4);
#pragma unroll
    for (int b=0; b<R; ++b) acc1[b][mt] = bv;
  }

#pragma unroll
  for (int b=0; b<R; ++b){
    const short* ps = Ps + (size_t)snd[b]*H + g*32;
    const short* pr = Pr + (size_t)rcv[b]*H + g*32;
    short8 vs[4], vr[4];
#pragma unroll
    for (int m2=0; m2<4; ++m2){
      vs[m2] = *(const short8*)(ps + m2*8);
      vr[m2] = *(const short8*)(pr + m2*8);
    }
#pragma unroll
    for (int m2=0; m2<4; ++m2)
#pragma unroll
      for (int r=0; r<4; ++r){
        acc1[b][2*m2][r]   += bf2f(vs[m2][r])   + bf2f(vr[m2][r]);
        acc1[b][2*m2+1][r] += bf2f(vs[m2][4+r]) + bf2f(vr[m2][4+r]);
      }
  }

#pragma unroll
  for (int ks=0; ks<4; ++ks){
    const int koff = ks*32 + g*8;
    short8 ein[R];
#pragma unroll
    for (int b=0; b<R; ++b){
      const float* sp = edge_feats + (size_t)rowc[b]*H;
      floatx4 f0 = *(const floatx4*)(sp + koff);
      floatx4 f1 = *(const floatx4*)(sp + koff + 4);
      ein[b][0]=f2bf(f0[0]); ein[b][1]=f2bf(f0[1]); ein[b][2]=f2bf(f0[2]); ein[b][3]=f2bf(f0[3]);
      ein[b][4]=f2bf(f1[0]); ein[b][5]=f2bf(f1[1]); ein[b][6]=f2bf(f1[2]); ein[b][7]=f2bf(f1[3]);
    }
#pragma unroll
    for (int mt=0; mt<8; ++mt){
      short8 wv = *(const short8*)(wef + ((ks*8+mt)*64 + l)*8);
#pragma unroll
      for (int b=0; b<R; ++b)
        acc1[b][mt] = __builtin_amdgcn_mfma_f32_16x16x32_bf16(wv, ein[b], acc1[b][mt], 0,0,0);
    }
  }

  // ---- relu + bf16 pack to LDS, XOR-swizzled (identical to validated code) ----
#pragma unroll
  for (int b=0; b<R; ++b){
    short* ldsw = lds_h + (w*R + b)*2048;
#pragma unroll
    for (int mt=0; mt<8; ++mt){
      short4v hv;
#pragma unroll
      for (int r=0; r<4; ++r){
        float v = acc1[b][mt][r];
        hv[r] = f2bf(v > 0.f ? v : 0.f);
      }
      int off = (lo*256 + mt*32 + g*8) ^ ((lo&7)<<4);
      *(short4v*)((char*)ldsw + off) = hv;
    }
  }

  // ---- phase 2: y^T = W2^T @ h^T ----
  floatx4 acc2[R][8];
#pragma unroll
  for (int mt=0; mt<8; ++mt){
    floatx4 bv = *(const floatx4*)(b2f + (mt*64+l)*4);
#pragma unroll
    for (int b=0; b<R; ++b) acc2[b][mt] = bv;
  }

#pragma unroll
  for (int s=0; s<4; ++s){
    short8 hb[R];
#pragma unroll
    for (int b=0; b<R; ++b){
      short* ldsw = lds_h + (w*R + b)*2048;
      int roff = (lo*256 + s*64 + g*16) ^ ((lo&7)<<4);
      hb[b] = *(const short8*)((char*)ldsw + roff);
    }
#pragma unroll
    for (int mt=0; mt<8; ++mt){
      short8 wv = *(const short8*)(w2f + ((s*8+mt)*64 + l)*8);
#pragma unroll
      for (int b=0; b<R; ++b)
        acc2[b][mt] = __builtin_amdgcn_mfma_f32_16x16x32_bf16(wv, hb[b], acc2[b][mt], 0,0,0);
    }
  }

  // ---- LayerNorm + residual + store ----
  float meanv[R], rsv[R];
#pragma unroll
  for (int b=0; b<R; ++b){
    float sum = 0.f, ssq = 0.f;
#pragma unroll
    for (int mt=0; mt<8; ++mt)
#pragma unroll
      for (int r=0; r<4; ++r){ float v = acc2[b][mt][r]; sum += v; ssq += v*v; }
    sum += __shfl_xor(sum, 16); ssq += __shfl_xor(ssq, 16);
    sum += __shfl_xor(sum, 32); ssq += __shfl_xor(ssq, 32);
    meanv[b] = sum * (1.f/H);
    float var = ssq * (1.f/H) - meanv[b]*meanv[b];
    rsv[b] = rsqrtf(var + 1e-5f);
  }

#pragma unroll
  for (int mt=0; mt<8; ++mt){
    floatx4 gv  = *(const floatx4*)(gf  + (mt*64+l)*4);
    floatx4 bgv = *(const floatx4*)(bgf + (mt*64+l)*4);
#pragma unroll
    for (int b=0; b<R; ++b){
      const float* resid = edge_feats + (size_t)rowc[b]*H;
      floatx4 ef = *(const floatx4*)(resid + mt*16 + g*4);
      floatx4 o;
#pragma unroll
      for (int r=0; r<4; ++r) o[r] = ef[r] + (acc2[b][mt][r]-meanv[b])*rsv[b]*gv[r] + bgv[r];
      if (valid[b]) *(floatx4*)(out_edge + (size_t)rowc[b]*H + mt*16 + g*4) = o;
    }
  }
}

// ---------- node kernel (unchanged structure, KS1=8, R=1) ----------
__global__ __launch_bounds__(256) void node_kernel(
    const float* __restrict__ node_feats,
    const short* __restrict__ w1f, const short* __restrict__ w2f,
    const float* __restrict__ b1f, const float* __restrict__ b2f,
    const float* __restrict__ gf,  const float* __restrict__ bgf,
    float* __restrict__ out_node)
{
  __shared__ short lds_h[4*2048];
  const int tid = threadIdx.x;
  const int w = tid>>6, l = tid&63, g = l>>4, lo = l&15;
  short* ldsw = lds_h + w*2048;

  int row = blockIdx.x*64 + w*16 + lo;
  bool valid = row < NN;
  int rowc = valid ? row : (NN-1);
  const float* sp0 = node_feats + (size_t)rowc*H;
  const float* sp1 = out_node   + (size_t)rowc*H;   // segsum acc

  floatx4 acc1[8];
#pragma unroll
  for (int mt=0; mt<8; ++mt) acc1[mt] = *(const floatx4*)(b1f + (mt*64+l)*4);

#pragma unroll
  for (int ks=0; ks<8; ++ks){
    const float* sp = (ks<4) ? sp0 : sp1;
    const int koff = (ks&3)*32 + g*8;
    floatx4 f0 = *(const floatx4*)(sp + koff);
    floatx4 f1 = *(const floatx4*)(sp + koff + 4);
    short8 ein;
    ein[0]=f2bf(f0[0]); ein[1]=f2bf(f0[1]); ein[2]=f2bf(f0[2]); ein[3]=f2bf(f0[3]);
    ein[4]=f2bf(f1[0]); ein[5]=f2bf(f1[1]); ein[6]=f2bf(f1[2]); ein[7]=f2bf(f1[3]);
#pragma unroll
    for (int mt=0; mt<8; ++mt){
      short8 wv = *(const short8*)(w1f + ((ks*8+mt)*64 + l)*8);
      acc1[mt] = __builtin_amdgcn_mfma_f32_16x16x32_bf16(wv, ein, acc1[mt], 0,0,0);
    }
  }

#pragma unroll
  for (int mt=0; mt<8; ++mt){
    short4v hv;
#pragma unroll
    for (int r=0; r<4; ++r){
      float v = acc1[mt][r];
      hv[r] = f2bf(v > 0.f ? v : 0.f);
    }
    int off = (lo*256 + mt*32 + g*8) ^ ((lo&7)<<4);
    *(short4v*)((char*)ldsw + off) = hv;
  }

  floatx4 acc2[8];
#pragma unroll
  for (int mt=0; mt<8; ++mt) acc2[mt] = *(const floatx4*)(b2f + (mt*64+l)*4);

#pragma unroll
  for (int s=0; s<4; ++s){
    int roff = (lo*256 + s*64 + g*16) ^ ((lo&7)<<4);
    short8 hb = *(const short8*)((char*)ldsw + roff);
#pragma unroll
    for (int mt=0; mt<8; ++mt){
      short8 wv = *(const short8*)(w2f + ((s*8+mt)*64 + l)*8);
      acc2[mt] = __builtin_amdgcn_mfma_f32_16x16x32_bf16(wv, hb, acc2[mt], 0,0,0);
    }
  }

  float sum = 0.f, ssq = 0.f;
#pragma unroll
  for (int mt=0; mt<8; ++mt)
#pragma unroll
    for (int r=0; r<4; ++r){ float v = acc2[mt][r]; sum += v; ssq += v*v; }
  sum += __shfl_xor(sum, 16); ssq += __shfl_xor(ssq, 16);
  sum += __shfl_xor(sum, 32); ssq += __shfl_xor(ssq, 32);
  const float mean = sum * (1.f/H);
  const float var  = ssq * (1.f/H) - mean*mean;
  const float rs   = rsqrtf(var + 1e-5f);

#pragma unroll
  for (int mt=0; mt<8; ++mt){
    floatx4 gv  = *(const floatx4*)(gf  + (mt*64+l)*4);
    floatx4 bgv = *(const floatx4*)(bgf + (mt*64+l)*4);
    floatx4 nf  = *(const floatx4*)(node_feats + (size_t)rowc*H + mt*16 + g*4);
    floatx4 o;
#pragma unroll
    for (int r=0; r<4; ++r) o[r] = nf[r] + (acc2[mt][r]-mean)*rs*gv[r] + bgv[r];
    if (valid) *(floatx4*)(out_node + (size_t)rowc*H + mt*16 + g*4) = o;
  }
}

extern "C" void kernel_launch(void* const* d_in, const int* in_sizes, int n_in,
                              void* d_out, int out_size, void* d_ws, size_t ws_size,
                              hipStream_t stream)
{
  const int*   edge_idx   = (const int*)  d_in[0];
  const float* node_feats = (const float*)d_in[1];
  const float* edge_feats = (const float*)d_in[2];
  const float* We1=(const float*)d_in[3];  const float* be1=(const float*)d_in[4];
  const float* We2=(const float*)d_in[5];  const float* be2=(const float*)d_in[6];
  const float* ge =(const float*)d_in[7];  const float* bge=(const float*)d_in[8];
  const float* Wn1=(const float*)d_in[9];  const float* bn1=(const float*)d_in[10];
  const float* Wn2=(const float*)d_in[11]; const float* bn2=(const float*)d_in[12];
  const float* gn =(const float*)d_in[13]; const float* bgn=(const float*)d_in[14];

  float* out_node = (float*)d_out;                    // doubles as segsum acc
  float* out_edge = out_node + (size_t)NN*H;

  char* ws = (char*)d_ws;
  short* wf      = (short*)ws;
  float* bf      = (float*)(ws + OFF_BF);
  short* Ps      = (short*)(ws + OFF_PS);
  short* Pr      = (short*)(ws + OFF_PR);
  int* cnt       = (int*)(ws + OFF_CNT);
  int* tmp       = (int*)(ws + OFF_TMP);
  int* rowstart  = (int*)(ws + OFF_RS);
  int* cursor    = (int*)(ws + OFF_CUR);
  int* blocksum  = (int*)(ws + OFF_BSUM);
  int* csr       = (int*)(ws + OFF_CSR);

  short* wsf  = wf;                 // We1 rows 0-127
  short* wrf  = wf + 16384;         // We1 rows 128-255
  short* wef  = wf + 32768;         // We1 rows 256-383
  short* w2f  = wf + 49152;         // We2
  short* wn1f = wf + 65536;         // Wn1 (8 ks)
  short* wn2f = wf + 98304;         // Wn2
  float* b1f  = bf;         float* b2f  = bf + 2048;
  float* gef  = bf + 4096;  float* bgef = bf + 6144;
  float* bn1f = bf + 8192;  float* bn2f = bf + 10240;
  float* gnf  = bf + 12288; float* bgnf = bf + 14336;

  zero_cnt_kernel<<<NB1, 256, 0, stream>>>(cnt);
  prep_kernel<<<(WF_TOTAL + BIASF_FLOATS + 255)/256, 256, 0, stream>>>(
      We1, We2, Wn1, Wn2, be1, be2, ge, bge, bn1, bn2, gn, bgn, wf, bf);

  // CSR build
  hist_kernel<<<(NE+255)/256, 256, 0, stream>>>(edge_idx, cnt);
  scan1_kernel<<<NB1, 256, 0, stream>>>(cnt, tmp, blocksum);
  scan2_kernel<<<1, 256, 0, stream>>>(blocksum);
  scan3_kernel<<<NB1, 256, 0, stream>>>(cnt, tmp, blocksum, rowstart, cursor);
  scatter_kernel<<<(NE+255)/256, 256, 0, stream>>>(edge_idx, cursor, csr);

  // node projections for edge phase-1 (Ps = nf@W_s, Pr = nf@W_r)
  pproj_kernel<<<(NN+63)/64, 256, 0, stream>>>(node_feats, wsf, wrf, Ps, Pr);

  // edge MLP
  edge_kernel<2><<<(NE + 127)/128, 256, 0, stream>>>(
      edge_idx, edge_feats, Ps, Pr, wef, w2f, b1f, b2f, gef, bgef, out_edge);

  // segment_sum into out_node (acc), then node MLP consumes + overwrites
  segsum_kernel<<<(NN+3)/4, 256, 0, stream>>>(csr, rowstart, cnt, edge_feats, out_node);

  node_kernel<<<(NN+63)/64, 256, 0, stream>>>(
      node_feats, wn1f, wn2f, bn1f, bn2f, gnf, bgnf, out_node);
}